// Round 7
// baseline (344.447 us; speedup 1.0000x reference)
//
#include <hip/hip_runtime.h>
#include <hip/hip_fp16.h>
#include <math.h>

#define Bq 4
#define Nq 512
#define Dq 4
#define Hq 256

typedef _Float16 f16x8 __attribute__((ext_vector_type(8)));
typedef float f32x4 __attribute__((ext_vector_type(4)));

// packed fp16 add + relu on 8 halves (v_pk_add_f16 + v_pk_max_f16)
__device__ __forceinline__ f16x8 hadd_relu(f16x8 u, f16x8 v) {
    f16x8 s = u + v;
    const f16x8 z = (f16x8)(_Float16)0.0f;
    return __builtin_elementwise_max(s, z);
}

__device__ __forceinline__ uint4 cvt8h(const float* p) {
    union { __half h[8]; uint4 u; } r;
#pragma unroll
    for (int i = 0; i < 8; ++i) r.h[i] = __float2half(p[i]);
    return r.u;
}

// ---------------- kernel 1: fused prep (U/V + weight transposes + agg zero)
// blocks 0..255: U/V for 8 rows each + zero a 2048-float slice of aggws
// blocks 256..319: coalesced 64x64 LDS-tile transpose of Wn1/Wn2/Wo1[4:]/We2
__global__ __launch_bounds__(256) void prep_all(
    const float* __restrict__ x, const float* __restrict__ We1,
    const float* __restrict__ be1, __half* __restrict__ U, __half* __restrict__ V,
    const float* __restrict__ Wn1, const float* __restrict__ Wn2,
    const float* __restrict__ Wo1, const float* __restrict__ We2,
    __half* __restrict__ Wt16, float* __restrict__ aggz) {
    const int bid = blockIdx.x;
    const int t = threadIdx.x;
    if (bid < 256) {
        // zero aggws (needed by edge_gemm's atomicAdd 2-way i-split)
        {
            float* az = aggz + (size_t)bid * 2048 + t * 8;
            const f32x4 z4 = (f32x4){0.f, 0.f, 0.f, 0.f};
            *(f32x4*)az = z4;
            *(f32x4*)(az + 4) = z4;
        }
        const float w0 = We1[0 * 256 + t], w1 = We1[1 * 256 + t];
        const float w2 = We1[2 * 256 + t], w3 = We1[3 * 256 + t];
        const float w4 = We1[4 * 256 + t], w5 = We1[5 * 256 + t];
        const float w6 = We1[6 * 256 + t], w7 = We1[7 * 256 + t];
        const float bv = be1[t];
#pragma unroll
        for (int r = 0; r < 8; ++r) {
            const int row = bid * 8 + r;
            const float* xp = x + row * Dq;
            const float x0 = xp[0], x1 = xp[1], x2 = xp[2], x3 = xp[3];
            float u = bv;
            u = fmaf(x0, w0, u); u = fmaf(x1, w1, u);
            u = fmaf(x2, w2, u); u = fmaf(x3, w3, u);
            float v = x0 * w4;
            v = fmaf(x1, w5, v); v = fmaf(x2, w6, v); v = fmaf(x3, w7, v);
            U[(size_t)row * Hq + t] = __float2half(u);
            V[(size_t)row * Hq + t] = __float2half(v);
        }
    } else {
        __shared__ float ld[64][65];       // padded: stride-65 reads conflict-free
        const int tid = bid - 256;         // 0..63
        const int mat = tid >> 4;          // 0..3
        const int tile = tid & 15;         // 4x4 tiles of 64x64
        const int k0 = (tile >> 2) * 64;
        const int n0 = (tile & 3) * 64;
        const float* W = (mat == 0) ? Wn1 : (mat == 1) ? Wn2
                       : (mat == 2) ? (Wo1 + 4 * 256) : We2;
        const int rr = t >> 6;             // 0..3
        const int cc = t & 63;             // 0..63
#pragma unroll
        for (int r = 0; r < 16; ++r) {
            const int row = r * 4 + rr;
            ld[row][cc] = W[(size_t)(k0 + row) * 256 + n0 + cc];  // coalesced read
        }
        __syncthreads();
#pragma unroll
        for (int r = 0; r < 16; ++r) {
            const int nrow = r * 4 + rr;
            Wt16[((size_t)mat * 256 + n0 + nrow) * 256 + k0 + cc] =
                __float2half(ld[cc][nrow]);
        }
    }
}

// ---------------- kernel 2: fused edge GEMM + adjacency aggregation --------
// R21: R19 structure + explicit distance-2 bf software pipeline.
// Diagnosis chain: LDS read throughput is per-CU (doesn't scale with
// occupancy); R13's 304 reads/block-chunk -> ~97us LDS floor (measured 144).
// Removing chunk-invariant bf reads (global L1/L2 instead) drops the LDS
// floor to ~56us < MFMA floor 66us (R18/R19 structure). R19's 262us was
// the bf VMEM latency: ~112 live regs forced just-in-time loads -> ~200cyc
// vmcnt stall per ks (model: 66 + stalls ~ 250 ~= measured 262).
// Fix: 3-slot rotating bf window (48 VGPR), load ks+2 while MFMA ks.
// All indices compile-time. zofs asm keeps LICM from hoisting 32 loads.
// Budget: arch ~158 + acc 80 = 238 <= 256 -> 2 waves/SIMD, no spill.
__global__ __launch_bounds__(256, 2) void edge_gemm(
    const __half* __restrict__ U, const __half* __restrict__ V,
    const __half* __restrict__ We2t, const float* __restrict__ be2,
    const float* __restrict__ adj, float* __restrict__ aggws) {
    __shared__ __align__(16) char smem[26624];
    __half* Us = (__half*)smem;                 //  8192 B: [16][256] swz
    __half* Vs = (__half*)(smem + 8192);        // 16384 B: [2][16][256] swz
    float* adjs = (float*)(smem + 24576);       //  2048 B: [2][16][16]
    float* red = (float*)(smem + 8192);         // aliases Vs, post-loop only

    const int bid = blockIdx.x;
    const int jt = bid & 31;            // low bits: co-resident blocks share hq
    const int ih = (bid >> 5) & 1;      // i-half (0: rows 0..255, 1: 256..511)
    const int hq_ = (bid >> 6) & 3;
    const int b = bid >> 8;
    const int h_base = hq_ * 64;
    const int j_base = jt * 16;
    const int i0 = ih * 256;
    const int t = threadIdx.x;
    const int lane = t & 63;
    const int w = t >> 6;               // 0..3
    const int q = lane >> 4;
    const int l15 = lane & 15;

    const __half* Vb = V + (size_t)b * Nq * Hq;
    const float* adjb = adj + (size_t)b * Nq * Nq;

    const int srow = t >> 4;            // 0..15
    const int sc0 = (t & 15) * 2;

    {   // Us staging (chunk-invariant j-rows)
        const uint4* gp = (const uint4*)(U + (size_t)(b * Nq + j_base + srow) * Hq);
        uint4 v0 = gp[sc0];
        uint4 v1 = gp[sc0 + 1];
        *(uint4*)&Us[srow * 256 + ((sc0 ^ srow) << 3)] = v0;
        *(uint4*)&Us[srow * 256 + (((sc0 + 1) ^ srow) << 3)] = v1;
    }

    float bias[4];
#pragma unroll
    for (int nt = 0; nt < 4; ++nt) bias[nt] = be2[h_base + nt * 16 + l15];

    f32x4 agg[4];
#pragma unroll
    for (int nt = 0; nt < 4; ++nt) agg[nt] = (f32x4){0.f, 0.f, 0.f, 0.f};

    uint4 pva, pvb; float pad_;
    {   // stage chunk 0 (i rows i0..i0+15)
        const uint4* gp = (const uint4*)(Vb + (size_t)(i0 + srow) * Hq);
        pva = gp[sc0]; pvb = gp[sc0 + 1];
        pad_ = adjb[(size_t)(i0 + srow) * Nq + j_base + (t & 15)];
        *(uint4*)&Vs[srow * 256 + ((sc0 ^ srow) << 3)] = pva;
        *(uint4*)&Vs[srow * 256 + (((sc0 + 1) ^ srow) << 3)] = pvb;
        adjs[t] = pad_;
    }
    {   // preload chunk 1
        const uint4* gp = (const uint4*)(Vb + (size_t)(i0 + 16 + srow) * Hq);
        pva = gp[sc0]; pvb = gp[sc0 + 1];
        pad_ = adjb[(size_t)(i0 + 16 + srow) * Nq + j_base + (t & 15)];
    }
    __syncthreads();

    const f32x4 zero4 = (f32x4){0.f, 0.f, 0.f, 0.f};
    // per-thread base into We2t16 h-slice: row = h_base+l15(+nt*16), col q*8(+ks*32)
    const __half* WrowBase = We2t + (size_t)(h_base + l15) * 256 + q * 8;

    for (int ch = 0; ch < 16; ++ch) {
        const int cur = ch & 1;
        const __half* Vcur = Vs + cur * 4096;
        const float* Acur = adjs + cur * 256;

        // opaque per-chunk offset: keeps bf loads inside the chunk loop
        int zofs = 0;
        asm volatile("" : "+v"(zofs));
        const __half* Wrow = WrowBase + zofs;

        f32x4 acc[4][4];
#pragma unroll
        for (int mi = 0; mi < 4; ++mi)
#pragma unroll
            for (int nt = 0; nt < 4; ++nt)
                acc[mi][nt] = (f32x4){bias[nt], bias[nt], bias[nt], bias[nt]};

        // distance-2 rotating bf window: slots for ks, ks+1, ks+2
        f16x8 bfp[3][4];
#pragma unroll
        for (int nt = 0; nt < 4; ++nt)
            bfp[0][nt] = *(const f16x8*)&Wrow[nt * 4096 + 0 * 32];
#pragma unroll
        for (int nt = 0; nt < 4; ++nt)
            bfp[1][nt] = *(const f16x8*)&Wrow[nt * 4096 + 1 * 32];

#pragma unroll
        for (int ks = 0; ks < 8; ++ks) {
            if (ks < 6) {   // prefetch bf for ks+2 (issued before this ks's MFMAs)
#pragma unroll
                for (int nt = 0; nt < 4; ++nt)
                    bfp[(ks + 2) % 3][nt] =
                        *(const f16x8*)&Wrow[nt * 4096 + (ks + 2) * 32];
            }
            const int c = ks * 4 + q;
            const f16x8 uvec = *(const f16x8*)&Us[l15 * 256 + ((c ^ l15) << 3)];
            f16x8 afrag[4];
#pragma unroll
            for (int mi = 0; mi < 4; ++mi) {
                const int iv = w * 4 + mi;
                const f16x8 vvec = *(const f16x8*)&Vcur[iv * 256 + ((c ^ iv) << 3)];
                afrag[mi] = hadd_relu(uvec, vvec);
            }
#pragma unroll
            for (int mi = 0; mi < 4; ++mi)
#pragma unroll
                for (int nt = 0; nt < 4; ++nt)
                    acc[mi][nt] = __builtin_amdgcn_mfma_f32_16x16x32_f16(
                        afrag[mi], bfp[ks % 3][nt], acc[mi][nt], 0, 0, 0);
        }

        // epilogue: agg[j,h] += adj[i,j] * relu(z) — vector form for pk-f32
#pragma unroll
        for (int mi = 0; mi < 4; ++mi) {
            const int iv = w * 4 + mi;
            const f32x4 av = *(const f32x4*)&Acur[iv * 16 + q * 4];
#pragma unroll
            for (int nt = 0; nt < 4; ++nt) {
                const f32x4 rel = __builtin_elementwise_max(acc[mi][nt], zero4);
                agg[nt] = av * rel + agg[nt];
            }
        }

        if (ch < 15) {
            const int nxt = cur ^ 1;
            *(uint4*)&Vs[nxt * 4096 + srow * 256 + ((sc0 ^ srow) << 3)] = pva;
            *(uint4*)&Vs[nxt * 4096 + srow * 256 + (((sc0 + 1) ^ srow) << 3)] = pvb;
            adjs[nxt * 256 + t] = pad_;
            if (ch < 14) {
                const int i_base = i0 + (ch + 2) * 16;
                const uint4* gp = (const uint4*)(Vb + (size_t)(i_base + srow) * Hq);
                pva = gp[sc0]; pvb = gp[sc0 + 1];
                pad_ = adjb[(size_t)(i_base + srow) * Nq + j_base + (t & 15)];
            }
        }
        __syncthreads();
    }

    // 4-way cross-wave reduction (red aliases Vs; loop-end barrier protects)
#pragma unroll
    for (int nt = 0; nt < 4; ++nt)
#pragma unroll
        for (int r = 0; r < 4; ++r)
            red[w * 1024 + (q * 4 + r) * 64 + nt * 16 + l15] = agg[nt][r];
    __syncthreads();
    {
        const int j = t >> 4;
        const int h0 = (t & 15) * 4;
        f32x4 s = *(const f32x4*)&red[0 * 1024 + j * 64 + h0];
        s += *(const f32x4*)&red[1 * 1024 + j * 64 + h0];
        s += *(const f32x4*)&red[2 * 1024 + j * 64 + h0];
        s += *(const f32x4*)&red[3 * 1024 + j * 64 + h0];
        float* dst = &aggws[(size_t)(b * Nq + j_base + j) * Hq + h_base + h0];
        // 2-way deterministic combine across i-halves (commutative f32 add)
        atomicAdd(dst + 0, s[0]);
        atomicAdd(dst + 1, s[1]);
        atomicAdd(dst + 2, s[2]);
        atomicAdd(dst + 3, s[3]);
    }
}

// ---------------- kernel 3: MFMA node-MLP tail + log_softmax --------------
// R11/R13 verbatim: 128 blocks x 16 nodes, per-wave h-slice 64.
__global__ __launch_bounds__(256) void tail_kernel(
    const float* __restrict__ aggws, const float* __restrict__ x,
    const __half* __restrict__ Wt16,
    const float* __restrict__ bn1, const float* __restrict__ bn2,
    const float* __restrict__ Wo1, const float* __restrict__ bo1,
    const float* __restrict__ Wo, const float* __restrict__ bo,
    float* __restrict__ out) {
    __shared__ __align__(16) __half actA[16 * 256];   // 8 KB
    __shared__ __align__(16) __half actB[16 * 256];   // 8 KB
    __shared__ float xs[16][4];
    __shared__ float part[4][16][4];
    __shared__ float s5[16][4];
    const int g0 = blockIdx.x * 16;
    const int t = threadIdx.x;
    const int lane = t & 63;
    const int w = t >> 6;
    const int q = lane >> 4;
    const int l15 = lane & 15;
    const int hb = w * 64;

    {
        const int row = t >> 4;
        const int g = (t & 15) * 2;
        const float* src = aggws + (size_t)(g0 + row) * 256;
        *(uint4*)&actA[row * 256 + ((g ^ row) << 3)] = cvt8h(src + g * 8);
        *(uint4*)&actA[row * 256 + (((g + 1) ^ row) << 3)] = cvt8h(src + g * 8 + 8);
    }
    if (t < 64) xs[t >> 2][t & 3] = x[(size_t)(g0 + (t >> 2)) * 4 + (t & 3)];
    __syncthreads();

    f32x4 acc[4];
    // layer n1
#pragma unroll
    for (int nt = 0; nt < 4; ++nt) {
        const float bv = bn1[hb + nt * 16 + l15];
        acc[nt] = (f32x4){bv, bv, bv, bv};
    }
#pragma unroll
    for (int ks = 0; ks < 8; ++ks) {
        const int c = ks * 4 + q;
        const f16x8 af = *(const f16x8*)&actA[l15 * 256 + ((c ^ l15) << 3)];
#pragma unroll
        for (int nt = 0; nt < 4; ++nt) {
            const f16x8 bf = *(const f16x8*)&Wt16[(size_t)(hb + nt * 16 + l15) * 256 + c * 8];
            acc[nt] = __builtin_amdgcn_mfma_f32_16x16x32_f16(af, bf, acc[nt], 0, 0, 0);
        }
    }
#pragma unroll
    for (int nt = 0; nt < 4; ++nt) {
        const int n = hb + nt * 16 + l15;
        const int g = n >> 3;
#pragma unroll
        for (int r = 0; r < 4; ++r) {
            const int row = q * 4 + r;
            actB[row * 256 + ((g ^ row) << 3) + (n & 7)] = __float2half(fmaxf(acc[nt][r], 0.f));
        }
    }
    __syncthreads();

    // layer n2
#pragma unroll
    for (int nt = 0; nt < 4; ++nt) {
        const float bv = bn2[hb + nt * 16 + l15];
        acc[nt] = (f32x4){bv, bv, bv, bv};
    }
#pragma unroll
    for (int ks = 0; ks < 8; ++ks) {
        const int c = ks * 4 + q;
        const f16x8 af = *(const f16x8*)&actB[l15 * 256 + ((c ^ l15) << 3)];
#pragma unroll
        for (int nt = 0; nt < 4; ++nt) {
            const f16x8 bf = *(const f16x8*)&Wt16[65536 + (size_t)(hb + nt * 16 + l15) * 256 + c * 8];
            acc[nt] = __builtin_amdgcn_mfma_f32_16x16x32_f16(af, bf, acc[nt], 0, 0, 0);
        }
    }
#pragma unroll
    for (int nt = 0; nt < 4; ++nt) {
        const int n = hb + nt * 16 + l15;
        const int g = n >> 3;
#pragma unroll
        for (int r = 0; r < 4; ++r) {
            const int row = q * 4 + r;
            actA[row * 256 + ((g ^ row) << 3) + (n & 7)] = __float2half(fmaxf(acc[nt][r], 0.f));
        }
    }
    __syncthreads();

    // layer o1 (x-part folded into init; no relu)
#pragma unroll
    for (int nt = 0; nt < 4; ++nt) {
        const int n = hb + nt * 16 + l15;
        const float bv = bo1[n];
        const float w0 = Wo1[0 * 256 + n], w1 = Wo1[1 * 256 + n];
        const float w2 = Wo1[2 * 256 + n], w3 = Wo1[3 * 256 + n];
#pragma unroll
        for (int r = 0; r < 4; ++r) {
            const int row = q * 4 + r;
            float v = bv;
            v = fmaf(xs[row][0], w0, v); v = fmaf(xs[row][1], w1, v);
            v = fmaf(xs[row][2], w2, v); v = fmaf(xs[row][3], w3, v);
            acc[nt][r] = v;
        }
    }
#pragma unroll
    for (int ks = 0; ks < 8; ++ks) {
        const int c = ks * 4 + q;
        const f16x8 af = *(const f16x8*)&actA[l15 * 256 + ((c ^ l15) << 3)];
#pragma unroll
        for (int nt = 0; nt < 4; ++nt) {
            const f16x8 bf = *(const f16x8*)&Wt16[2 * 65536 + (size_t)(hb + nt * 16 + l15) * 256 + c * 8];
            acc[nt] = __builtin_amdgcn_mfma_f32_16x16x32_f16(af, bf, acc[nt], 0, 0, 0);
        }
    }

    // layer o + log_softmax
    float p[4][4];
#pragma unroll
    for (int r = 0; r < 4; ++r)
#pragma unroll
        for (int d = 0; d < 4; ++d) p[r][d] = 0.f;
#pragma unroll
    for (int nt = 0; nt < 4; ++nt) {
        const int n = hb + nt * 16 + l15;
        const float4 wv = *(const float4*)&Wo[n * 4];
#pragma unroll
        for (int r = 0; r < 4; ++r) {
            p[r][0] = fmaf(acc[nt][r], wv.x, p[r][0]);
            p[r][1] = fmaf(acc[nt][r], wv.y, p[r][1]);
            p[r][2] = fmaf(acc[nt][r], wv.z, p[r][2]);
            p[r][3] = fmaf(acc[nt][r], wv.w, p[r][3]);
        }
    }
#pragma unroll
    for (int off = 1; off < 16; off <<= 1)
#pragma unroll
        for (int r = 0; r < 4; ++r)
#pragma unroll
            for (int d = 0; d < 4; ++d)
                p[r][d] += __shfl_xor(p[r][d], off);
    if (l15 == 0) {
#pragma unroll
        for (int r = 0; r < 4; ++r)
#pragma unroll
            for (int d = 0; d < 4; ++d) part[w][q * 4 + r][d] = p[r][d];
    }
    __syncthreads();
    if (t < 64) {
        const int row = t >> 2;
        const int d = t & 3;
        s5[row][d] = part[0][row][d] + part[1][row][d] + part[2][row][d]
                   + part[3][row][d] + bo[d];
    }
    __syncthreads();
    if (t < 16) {
        const float v0 = s5[t][0], v1 = s5[t][1], v2 = s5[t][2], v3 = s5[t][3];
        const float m = fmaxf(fmaxf(v0, v1), fmaxf(v2, v3));
        const float s = expf(v0 - m) + expf(v1 - m) + expf(v2 - m) + expf(v3 - m);
        const float lse = m + logf(s);
        float* op = out + (size_t)(g0 + t) * 4;
        op[0] = v0 - lse; op[1] = v1 - lse; op[2] = v2 - lse; op[3] = v3 - lse;
    }
}

extern "C" void kernel_launch(void* const* d_in, const int* in_sizes, int n_in,
                              void* d_out, int out_size, void* d_ws, size_t ws_size,
                              hipStream_t stream) {
    const float* x   = (const float*)d_in[0];
    const float* adj = (const float*)d_in[1];
    const float* We1 = (const float*)d_in[2];
    const float* be1 = (const float*)d_in[3];
    const float* We2 = (const float*)d_in[4];
    const float* be2 = (const float*)d_in[5];
    const float* Wn1 = (const float*)d_in[6];
    const float* bn1 = (const float*)d_in[7];
    const float* Wn2 = (const float*)d_in[8];
    const float* bn2 = (const float*)d_in[9];
    const float* Wo1 = (const float*)d_in[10];
    const float* bo1 = (const float*)d_in[11];
    const float* Wo  = (const float*)d_in[12];
    const float* bo  = (const float*)d_in[13];
    float* out = (float*)d_out;

    // ws: U fp16 1MB | V fp16 1MB | agg f32 2MB | Wt16 fp16 512KB (4 mats)
    __half* U = (__half*)d_ws;
    __half* V = U + (size_t)Bq * Nq * Hq;
    float* aggws = (float*)((char*)d_ws + (size_t)2 * Bq * Nq * Hq * sizeof(__half));
    __half* Wt16 = (__half*)((char*)d_ws + (size_t)4 * 1024 * 1024);
    __half* We2t = Wt16 + (size_t)3 * 65536;   // mat 3: We2 transposed fp16

    prep_all<<<320, 256, 0, stream>>>(x, We1, be1, U, V, Wn1, Wn2, Wo1, We2, Wt16, aggws);
    edge_gemm<<<1024, 256, 0, stream>>>(U, V, We2t, be2, adj, aggws);
    tail_kernel<<<128, 256, 0, stream>>>(aggws, x, Wt16, bn1, bn2, Wo1, bo1, Wo, bo, out);
}

// Round 9
// 323.500 us; speedup vs baseline: 1.0648x; 1.0648x over previous
//
#include <hip/hip_runtime.h>
#include <hip/hip_fp16.h>
#include <math.h>

#define Bq 4
#define Nq 512
#define Dq 4
#define Hq 256

typedef _Float16 f16x8 __attribute__((ext_vector_type(8)));
typedef float f32x4 __attribute__((ext_vector_type(4)));

// packed fp16 add + relu on 8 halves (v_pk_add_f16 + v_pk_max_f16)
__device__ __forceinline__ f16x8 hadd_relu(f16x8 u, f16x8 v) {
    f16x8 s = u + v;
    const f16x8 z = (f16x8)(_Float16)0.0f;
    return __builtin_elementwise_max(s, z);
}

__device__ __forceinline__ uint4 cvt8h(const float* p) {
    union { __half h[8]; uint4 u; } r;
#pragma unroll
    for (int i = 0; i < 8; ++i) r.h[i] = __float2half(p[i]);
    return r.u;
}

// ---------------- kernel 1: fused prep (U/V + tail-weight transpose) ------
// Round-0 verbatim (proven).
__global__ __launch_bounds__(256) void prep_all(
    const float* __restrict__ x, const float* __restrict__ We1,
    const float* __restrict__ be1, __half* __restrict__ U, __half* __restrict__ V,
    const float* __restrict__ Wn1, const float* __restrict__ Wn2,
    const float* __restrict__ Wo1, __half* __restrict__ Wt16) {
    const int bid = blockIdx.x;
    const int t = threadIdx.x;
    if (bid < 256) {
        const float w0 = We1[0 * 256 + t], w1 = We1[1 * 256 + t];
        const float w2 = We1[2 * 256 + t], w3 = We1[3 * 256 + t];
        const float w4 = We1[4 * 256 + t], w5 = We1[5 * 256 + t];
        const float w6 = We1[6 * 256 + t], w7 = We1[7 * 256 + t];
        const float bv = be1[t];
#pragma unroll
        for (int r = 0; r < 8; ++r) {
            const int row = bid * 8 + r;
            const float* xp = x + row * Dq;
            const float x0 = xp[0], x1 = xp[1], x2 = xp[2], x3 = xp[3];
            float u = bv;
            u = fmaf(x0, w0, u); u = fmaf(x1, w1, u);
            u = fmaf(x2, w2, u); u = fmaf(x3, w3, u);
            float v = x0 * w4;
            v = fmaf(x1, w5, v); v = fmaf(x2, w6, v); v = fmaf(x3, w7, v);
            U[(size_t)row * Hq + t] = __float2half(u);
            V[(size_t)row * Hq + t] = __float2half(v);
        }
    } else {
        __shared__ float ld[64][65];       // padded: stride-65 reads conflict-free
        const int tid = bid - 256;         // 0..47
        const int mat = tid >> 4;          // 0..2
        const int tile = tid & 15;         // 4x4 tiles of 64x64
        const int k0 = (tile >> 2) * 64;
        const int n0 = (tile & 3) * 64;
        const float* W = (mat == 0) ? Wn1 : (mat == 1) ? Wn2 : (Wo1 + 4 * 256);
        const int rr = t >> 6;             // 0..3
        const int cc = t & 63;             // 0..63
#pragma unroll
        for (int r = 0; r < 16; ++r) {
            const int row = r * 4 + rr;
            ld[row][cc] = W[(size_t)(k0 + row) * 256 + n0 + cc];  // coalesced read
        }
        __syncthreads();
#pragma unroll
        for (int r = 0; r < 16; ++r) {
            const int nrow = r * 4 + rr;
            Wt16[((size_t)mat * 256 + n0 + nrow) * 256 + k0 + cc] =
                __float2half(ld[cc][nrow]);
        }
    }
}

// ---------------- kernel 2: fused edge GEMM + adjacency aggregation --------
// R22 (resubmit after container failure): Round-0 proven structure (144us,
// MfmaUtil 43 + VALUBusy 51 = 94% issue-saturated) + ONE mechanism:
// quad-buffered Vs/adjs so __syncthreads drops 32 -> 16 (barrier skew was
// the residual idle), plus setprio(1) around the MFMA ks-loop (2
// independent blocks/CU = phase diversity, the regime where setprio
// measured positive).
// R16-R21 lessons baked in: no launch_bounds>2 (64-VGPR clamp), no
// global-bf (latency trap at 2 waves/SIMD), no occupancy chase (register
// law: acc 80 + arch ~120 -> 2 waves/SIMD immovable). LDS 77824B -> still
// 2 blocks/CU. Held-prefetch regs +9 -> arch ~130 + acc 80 = 210 <= 256.
__global__ __launch_bounds__(256, 2) void edge_gemm(
    const __half* __restrict__ U, const __half* __restrict__ V,
    const float* __restrict__ We2, const float* __restrict__ be2,
    const float* __restrict__ adj, float* __restrict__ aggws) {
    __shared__ __align__(16) char smem[77824];
    __half* Wt = (__half*)smem;                 // 32768 B: [64 n][256 k swz]
    __half* Us = (__half*)(smem + 32768);       //  8192 B: [16][256] swz
    __half* Vs = (__half*)(smem + 40960);       // 32768 B: [4][16][256] swz
    float* adjs = (float*)(smem + 73728);       //  4096 B: [4][16][16]
    float* red = (float*)(smem + 40960);        // aliases Vs, post-loop only

    const int bid = blockIdx.x;
    const int hq_ = bid & 3;
    const int jt = (bid >> 2) & 31;
    const int b = bid >> 7;
    const int h_base = hq_ * 64;
    const int j_base = jt * 16;
    const int t = threadIdx.x;
    const int lane = t & 63;
    const int w = t >> 6;
    const int q = lane >> 4;
    const int l15 = lane & 15;

    const __half* Vb = V + (size_t)b * Nq * Hq;
    const float* adjb = adj + (size_t)b * Nq * Nq;

    const int srow = t >> 4;
    const int sc0 = (t & 15) * 2;

    {   // Wt staging (Round-0 verbatim)
        const int n = t & 63;
        const int swz = n & 31;
        for (int kk = (t >> 6); kk < 256; kk += 4) {
            float val = We2[kk * 256 + h_base + n];
            Wt[n * 256 + ((((kk >> 3) ^ swz)) << 3) + (kk & 7)] = __float2half(val);
        }
    }
    {   // Us staging (Round-0 verbatim)
        const uint4* gp = (const uint4*)(U + (size_t)(b * Nq + j_base + srow) * Hq);
        uint4 v0 = gp[sc0];
        uint4 v1 = gp[sc0 + 1];
        *(uint4*)&Us[srow * 256 + ((sc0 ^ srow) << 3)] = v0;
        *(uint4*)&Us[srow * 256 + (((sc0 + 1) ^ srow) << 3)] = v1;
    }

    float bias[4];
#pragma unroll
    for (int nt = 0; nt < 4; ++nt) bias[nt] = be2[h_base + nt * 16 + l15];

    f32x4 agg[4];
#pragma unroll
    for (int nt = 0; nt < 4; ++nt) agg[nt] = (f32x4){0.f, 0.f, 0.f, 0.f};

    const f32x4 zero4 = (f32x4){0.f, 0.f, 0.f, 0.f};

    // two held-prefetch register sets: A = even chunks, B = odd chunks
    uint4 pvaA, pvbA; float padA;
    uint4 pvaB, pvbB; float padB;

    {   // chunk 0 -> buf0
        const uint4* gp = (const uint4*)(Vb + (size_t)srow * Hq);
        pvaA = gp[sc0]; pvbA = gp[sc0 + 1];
        padA = adjb[(size_t)srow * Nq + j_base + (t & 15)];
        *(uint4*)&Vs[0 * 4096 + srow * 256 + ((sc0 ^ srow) << 3)] = pvaA;
        *(uint4*)&Vs[0 * 4096 + srow * 256 + (((sc0 + 1) ^ srow) << 3)] = pvbA;
        adjs[0 * 256 + t] = padA;
    }
    {   // chunk 1 -> buf1
        const uint4* gp = (const uint4*)(Vb + (size_t)(16 + srow) * Hq);
        pvaB = gp[sc0]; pvbB = gp[sc0 + 1];
        padB = adjb[(size_t)(16 + srow) * Nq + j_base + (t & 15)];
        *(uint4*)&Vs[1 * 4096 + srow * 256 + ((sc0 ^ srow) << 3)] = pvaB;
        *(uint4*)&Vs[1 * 4096 + srow * 256 + (((sc0 + 1) ^ srow) << 3)] = pvbB;
        adjs[1 * 256 + t] = padB;
    }
    {   // prefetch chunk 2 -> regs A
        const uint4* gp = (const uint4*)(Vb + (size_t)(32 + srow) * Hq);
        pvaA = gp[sc0]; pvbA = gp[sc0 + 1];
        padA = adjb[(size_t)(32 + srow) * Nq + j_base + (t & 15)];
    }
    {   // prefetch chunk 3 -> regs B
        const uint4* gp = (const uint4*)(Vb + (size_t)(48 + srow) * Hq);
        pvaB = gp[sc0]; pvbB = gp[sc0 + 1];
        padB = adjb[(size_t)(48 + srow) * Nq + j_base + (t & 15)];
    }
    __syncthreads();

    // per-chunk compute (Round-0 verbatim inner loop)
    auto compute_chunk = [&](const __half* Vcur, const float* Acur) {
        f32x4 acc[4][4];
#pragma unroll
        for (int mi = 0; mi < 4; ++mi)
#pragma unroll
            for (int nt = 0; nt < 4; ++nt)
                acc[mi][nt] = (f32x4){bias[nt], bias[nt], bias[nt], bias[nt]};

        __builtin_amdgcn_s_setprio(1);
#pragma unroll
        for (int ks = 0; ks < 8; ++ks) {
            const int c = ks * 4 + q;
            const f16x8 uvec = *(const f16x8*)&Us[l15 * 256 + ((c ^ l15) << 3)];
            f16x8 afrag[4];
#pragma unroll
            for (int mi = 0; mi < 4; ++mi) {
                const int iv = w * 4 + mi;
                const f16x8 vvec = *(const f16x8*)&Vcur[iv * 256 + ((c ^ iv) << 3)];
                afrag[mi] = hadd_relu(uvec, vvec);
            }
            f16x8 bf[4];
#pragma unroll
            for (int nt = 0; nt < 4; ++nt) {
                const int rn = nt * 16 + l15;
                bf[nt] = *(const f16x8*)&Wt[rn * 256 + ((c ^ (rn & 31)) << 3)];
            }
#pragma unroll
            for (int mi = 0; mi < 4; ++mi)
#pragma unroll
                for (int nt = 0; nt < 4; ++nt)
                    acc[mi][nt] = __builtin_amdgcn_mfma_f32_16x16x32_f16(
                        afrag[mi], bf[nt], acc[mi][nt], 0, 0, 0);
        }
        __builtin_amdgcn_s_setprio(0);

        // epilogue: agg[j,h] += adj[i,j] * relu(z)
#pragma unroll
        for (int mi = 0; mi < 4; ++mi) {
            const int iv = w * 4 + mi;
            const f32x4 av = *(const f32x4*)&Acur[iv * 16 + q * 4];
#pragma unroll
            for (int nt = 0; nt < 4; ++nt) {
                const f32x4 rel = __builtin_elementwise_max(acc[mi][nt], zero4);
                agg[nt] = av * rel + agg[nt];
            }
        }
    };

    // 16 pairs, ONE barrier per pair (chunks 2p, 2p+1)
    for (int pair = 0; pair < 16; ++pair) {
        const int cur = (pair & 1) * 2;
        const int nxt = ((pair + 1) & 1) * 2;

        // chunk 2p from buf[cur]
        compute_chunk(Vs + cur * 4096, adjs + cur * 256);
        if (pair < 15) {
            // write held chunk 2p+2 -> buf[nxt]
            *(uint4*)&Vs[nxt * 4096 + srow * 256 + ((sc0 ^ srow) << 3)] = pvaA;
            *(uint4*)&Vs[nxt * 4096 + srow * 256 + (((sc0 + 1) ^ srow) << 3)] = pvbA;
            adjs[nxt * 256 + t] = padA;
            if (pair < 14) {   // load chunk 2p+4 -> regs A
                const int i_base = (2 * pair + 4) * 16;
                const uint4* gp = (const uint4*)(Vb + (size_t)(i_base + srow) * Hq);
                pvaA = gp[sc0]; pvbA = gp[sc0 + 1];
                padA = adjb[(size_t)(i_base + srow) * Nq + j_base + (t & 15)];
            }
        }

        // chunk 2p+1 from buf[cur+1]
        compute_chunk(Vs + (cur + 1) * 4096, adjs + (cur + 1) * 256);
        if (pair < 15) {
            // write held chunk 2p+3 -> buf[nxt+1]
            *(uint4*)&Vs[(nxt + 1) * 4096 + srow * 256 + ((sc0 ^ srow) << 3)] = pvaB;
            *(uint4*)&Vs[(nxt + 1) * 4096 + srow * 256 + (((sc0 + 1) ^ srow) << 3)] = pvbB;
            adjs[(nxt + 1) * 256 + t] = padB;
            if (pair < 14) {   // load chunk 2p+5 -> regs B
                const int i_base = (2 * pair + 5) * 16;
                const uint4* gp = (const uint4*)(Vb + (size_t)(i_base + srow) * Hq);
                pvaB = gp[sc0]; pvbB = gp[sc0 + 1];
                padB = adjb[(size_t)(i_base + srow) * Nq + j_base + (t & 15)];
            }
        }
        __syncthreads();
    }

    // 4-way cross-wave reduction (red aliases Vs; final pair barrier protects)
#pragma unroll
    for (int nt = 0; nt < 4; ++nt)
#pragma unroll
        for (int r = 0; r < 4; ++r)
            red[w * 1024 + (q * 4 + r) * 64 + nt * 16 + l15] = agg[nt][r];
    __syncthreads();
    {
        const int j = t >> 4;
        const int h0 = (t & 15) * 4;
        f32x4 s = *(const f32x4*)&red[0 * 1024 + j * 64 + h0];
        s += *(const f32x4*)&red[1 * 1024 + j * 64 + h0];
        s += *(const f32x4*)&red[2 * 1024 + j * 64 + h0];
        s += *(const f32x4*)&red[3 * 1024 + j * 64 + h0];
        *(f32x4*)&aggws[(size_t)(b * Nq + j_base + j) * Hq + h_base + h0] = s;
    }
}

// ---------------- kernel 3: MFMA node-MLP tail + log_softmax --------------
// Round-0 verbatim: 128 blocks x 16 nodes, per-wave h-slice 64.
__global__ __launch_bounds__(256) void tail_kernel(
    const float* __restrict__ aggws, const float* __restrict__ x,
    const __half* __restrict__ Wt16,
    const float* __restrict__ bn1, const float* __restrict__ bn2,
    const float* __restrict__ Wo1, const float* __restrict__ bo1,
    const float* __restrict__ Wo, const float* __restrict__ bo,
    float* __restrict__ out) {
    __shared__ __align__(16) __half actA[16 * 256];   // 8 KB
    __shared__ __align__(16) __half actB[16 * 256];   // 8 KB
    __shared__ float xs[16][4];
    __shared__ float part[4][16][4];
    __shared__ float s5[16][4];
    const int g0 = blockIdx.x * 16;
    const int t = threadIdx.x;
    const int lane = t & 63;
    const int w = t >> 6;
    const int q = lane >> 4;
    const int l15 = lane & 15;
    const int hb = w * 64;

    {
        const int row = t >> 4;
        const int g = (t & 15) * 2;
        const float* src = aggws + (size_t)(g0 + row) * 256;
        *(uint4*)&actA[row * 256 + ((g ^ row) << 3)] = cvt8h(src + g * 8);
        *(uint4*)&actA[row * 256 + (((g + 1) ^ row) << 3)] = cvt8h(src + g * 8 + 8);
    }
    if (t < 64) xs[t >> 2][t & 3] = x[(size_t)(g0 + (t >> 2)) * 4 + (t & 3)];
    __syncthreads();

    f32x4 acc[4];
    // layer n1
#pragma unroll
    for (int nt = 0; nt < 4; ++nt) {
        const float bv = bn1[hb + nt * 16 + l15];
        acc[nt] = (f32x4){bv, bv, bv, bv};
    }
#pragma unroll
    for (int ks = 0; ks < 8; ++ks) {
        const int c = ks * 4 + q;
        const f16x8 af = *(const f16x8*)&actA[l15 * 256 + ((c ^ l15) << 3)];
#pragma unroll
        for (int nt = 0; nt < 4; ++nt) {
            const f16x8 bf = *(const f16x8*)&Wt16[(size_t)(hb + nt * 16 + l15) * 256 + c * 8];
            acc[nt] = __builtin_amdgcn_mfma_f32_16x16x32_f16(af, bf, acc[nt], 0, 0, 0);
        }
    }
#pragma unroll
    for (int nt = 0; nt < 4; ++nt) {
        const int n = hb + nt * 16 + l15;
        const int g = n >> 3;
#pragma unroll
        for (int r = 0; r < 4; ++r) {
            const int row = q * 4 + r;
            actB[row * 256 + ((g ^ row) << 3) + (n & 7)] = __float2half(fmaxf(acc[nt][r], 0.f));
        }
    }
    __syncthreads();

    // layer n2
#pragma unroll
    for (int nt = 0; nt < 4; ++nt) {
        const float bv = bn2[hb + nt * 16 + l15];
        acc[nt] = (f32x4){bv, bv, bv, bv};
    }
#pragma unroll
    for (int ks = 0; ks < 8; ++ks) {
        const int c = ks * 4 + q;
        const f16x8 af = *(const f16x8*)&actB[l15 * 256 + ((c ^ l15) << 3)];
#pragma unroll
        for (int nt = 0; nt < 4; ++nt) {
            const f16x8 bf = *(const f16x8*)&Wt16[65536 + (size_t)(hb + nt * 16 + l15) * 256 + c * 8];
            acc[nt] = __builtin_amdgcn_mfma_f32_16x16x32_f16(af, bf, acc[nt], 0, 0, 0);
        }
    }
#pragma unroll
    for (int nt = 0; nt < 4; ++nt) {
        const int n = hb + nt * 16 + l15;
        const int g = n >> 3;
#pragma unroll
        for (int r = 0; r < 4; ++r) {
            const int row = q * 4 + r;
            actA[row * 256 + ((g ^ row) << 3) + (n & 7)] = __float2half(fmaxf(acc[nt][r], 0.f));
        }
    }
    __syncthreads();

    // layer o1 (x-part folded into init; no relu)
#pragma unroll
    for (int nt = 0; nt < 4; ++nt) {
        const int n = hb + nt * 16 + l15;
        const float bv = bo1[n];
        const float w0 = Wo1[0 * 256 + n], w1 = Wo1[1 * 256 + n];
        const float w2 = Wo1[2 * 256 + n], w3 = Wo1[3 * 256 + n];
#pragma unroll
        for (int r = 0; r < 4; ++r) {
            const int row = q * 4 + r;
            float v = bv;
            v = fmaf(xs[row][0], w0, v); v = fmaf(xs[row][1], w1, v);
            v = fmaf(xs[row][2], w2, v); v = fmaf(xs[row][3], w3, v);
            acc[nt][r] = v;
        }
    }
#pragma unroll
    for (int ks = 0; ks < 8; ++ks) {
        const int c = ks * 4 + q;
        const f16x8 af = *(const f16x8*)&actA[l15 * 256 + ((c ^ l15) << 3)];
#pragma unroll
        for (int nt = 0; nt < 4; ++nt) {
            const f16x8 bf = *(const f16x8*)&Wt16[2 * 65536 + (size_t)(hb + nt * 16 + l15) * 256 + c * 8];
            acc[nt] = __builtin_amdgcn_mfma_f32_16x16x32_f16(af, bf, acc[nt], 0, 0, 0);
        }
    }

    // layer o + log_softmax
    float p[4][4];
#pragma unroll
    for (int r = 0; r < 4; ++r)
#pragma unroll
        for (int d = 0; d < 4; ++d) p[r][d] = 0.f;
#pragma unroll
    for (int nt = 0; nt < 4; ++nt) {
        const int n = hb + nt * 16 + l15;
        const float4 wv = *(const float4*)&Wo[n * 4];
#pragma unroll
        for (int r = 0; r < 4; ++r) {
            p[r][0] = fmaf(acc[nt][r], wv.x, p[r][0]);
            p[r][1] = fmaf(acc[nt][r], wv.y, p[r][1]);
            p[r][2] = fmaf(acc[nt][r], wv.z, p[r][2]);
            p[r][3] = fmaf(acc[nt][r], wv.w, p[r][3]);
        }
    }
#pragma unroll
    for (int off = 1; off < 16; off <<= 1)
#pragma unroll
        for (int r = 0; r < 4; ++r)
#pragma unroll
            for (int d = 0; d < 4; ++d)
                p[r][d] += __shfl_xor(p[r][d], off);
    if (l15 == 0) {
#pragma unroll
        for (int r = 0; r < 4; ++r)
#pragma unroll
            for (int d = 0; d < 4; ++d) part[w][q * 4 + r][d] = p[r][d];
    }
    __syncthreads();
    if (t < 64) {
        const int row = t >> 2;
        const int d = t & 3;
        s5[row][d] = part[0][row][d] + part[1][row][d] + part[2][row][d]
                   + part[3][row][d] + bo[d];
    }
    __syncthreads();
    if (t < 16) {
        const float v0 = s5[t][0], v1 = s5[t][1], v2 = s5[t][2], v3 = s5[t][3];
        const float m = fmaxf(fmaxf(v0, v1), fmaxf(v2, v3));
        const float s = expf(v0 - m) + expf(v1 - m) + expf(v2 - m) + expf(v3 - m);
        const float lse = m + logf(s);
        float* op = out + (size_t)(g0 + t) * 4;
        op[0] = v0 - lse; op[1] = v1 - lse; op[2] = v2 - lse; op[3] = v3 - lse;
    }
}

extern "C" void kernel_launch(void* const* d_in, const int* in_sizes, int n_in,
                              void* d_out, int out_size, void* d_ws, size_t ws_size,
                              hipStream_t stream) {
    const float* x   = (const float*)d_in[0];
    const float* adj = (const float*)d_in[1];
    const float* We1 = (const float*)d_in[2];
    const float* be1 = (const float*)d_in[3];
    const float* We2 = (const float*)d_in[4];
    const float* be2 = (const float*)d_in[5];
    const float* Wn1 = (const float*)d_in[6];
    const float* bn1 = (const float*)d_in[7];
    const float* Wn2 = (const float*)d_in[8];
    const float* bn2 = (const float*)d_in[9];
    const float* Wo1 = (const float*)d_in[10];
    const float* bo1 = (const float*)d_in[11];
    const float* Wo  = (const float*)d_in[12];
    const float* bo  = (const float*)d_in[13];
    float* out = (float*)d_out;

    // ws: U fp16 1MB | V fp16 1MB | agg f32 2MB | Wt16 fp16 384KB
    __half* U = (__half*)d_ws;
    __half* V = U + (size_t)Bq * Nq * Hq;
    float* aggws = (float*)((char*)d_ws + (size_t)2 * Bq * Nq * Hq * sizeof(__half));
    __half* Wt16 = (__half*)((char*)d_ws + (size_t)4 * 1024 * 1024);

    prep_all<<<304, 256, 0, stream>>>(x, We1, be1, U, V, Wn1, Wn2, Wo1, Wt16);
    edge_gemm<<<512, 256, 0, stream>>>(U, V, We2, be2, adj, aggws);
    tail_kernel<<<128, 256, 0, stream>>>(aggws, x, Wt16, bn1, bn2, Wo1, bo1, Wo, bo, out);
}

// Round 10
// 218.160 us; speedup vs baseline: 1.5789x; 1.4829x over previous
//
#include <hip/hip_runtime.h>
#include <hip/hip_fp16.h>
#include <math.h>

#define Bq 4
#define Nq 512
#define Dq 4
#define Hq 256

typedef _Float16 f16x8 __attribute__((ext_vector_type(8)));
typedef float f32x4 __attribute__((ext_vector_type(4)));

// packed fp16 add + relu on 8 halves (v_pk_add_f16 + v_pk_max_f16)
__device__ __forceinline__ f16x8 hadd_relu(f16x8 u, f16x8 v) {
    f16x8 s = u + v;
    const f16x8 z = (f16x8)(_Float16)0.0f;
    return __builtin_elementwise_max(s, z);
}

__device__ __forceinline__ uint4 cvt8h(const float* p) {
    union { __half h[8]; uint4 u; } r;
#pragma unroll
    for (int i = 0; i < 8; ++i) r.h[i] = __float2half(p[i]);
    return r.u;
}

// ---------------- kernel 1: fused prep (U/V + tail-weight transpose) ------
// Round-0 verbatim (proven).
__global__ __launch_bounds__(256) void prep_all(
    const float* __restrict__ x, const float* __restrict__ We1,
    const float* __restrict__ be1, __half* __restrict__ U, __half* __restrict__ V,
    const float* __restrict__ Wn1, const float* __restrict__ Wn2,
    const float* __restrict__ Wo1, __half* __restrict__ Wt16) {
    const int bid = blockIdx.x;
    const int t = threadIdx.x;
    if (bid < 256) {
        const float w0 = We1[0 * 256 + t], w1 = We1[1 * 256 + t];
        const float w2 = We1[2 * 256 + t], w3 = We1[3 * 256 + t];
        const float w4 = We1[4 * 256 + t], w5 = We1[5 * 256 + t];
        const float w6 = We1[6 * 256 + t], w7 = We1[7 * 256 + t];
        const float bv = be1[t];
#pragma unroll
        for (int r = 0; r < 8; ++r) {
            const int row = bid * 8 + r;
            const float* xp = x + row * Dq;
            const float x0 = xp[0], x1 = xp[1], x2 = xp[2], x3 = xp[3];
            float u = bv;
            u = fmaf(x0, w0, u); u = fmaf(x1, w1, u);
            u = fmaf(x2, w2, u); u = fmaf(x3, w3, u);
            float v = x0 * w4;
            v = fmaf(x1, w5, v); v = fmaf(x2, w6, v); v = fmaf(x3, w7, v);
            U[(size_t)row * Hq + t] = __float2half(u);
            V[(size_t)row * Hq + t] = __float2half(v);
        }
    } else {
        __shared__ float ld[64][65];       // padded: stride-65 reads conflict-free
        const int tid = bid - 256;         // 0..47
        const int mat = tid >> 4;          // 0..2
        const int tile = tid & 15;         // 4x4 tiles of 64x64
        const int k0 = (tile >> 2) * 64;
        const int n0 = (tile & 3) * 64;
        const float* W = (mat == 0) ? Wn1 : (mat == 1) ? Wn2 : (Wo1 + 4 * 256);
        const int rr = t >> 6;             // 0..3
        const int cc = t & 63;             // 0..63
#pragma unroll
        for (int r = 0; r < 16; ++r) {
            const int row = r * 4 + rr;
            ld[row][cc] = W[(size_t)(k0 + row) * 256 + n0 + cc];  // coalesced read
        }
        __syncthreads();
#pragma unroll
        for (int r = 0; r < 16; ++r) {
            const int nrow = r * 4 + rr;
            Wt16[((size_t)mat * 256 + n0 + nrow) * 256 + k0 + cc] =
                __float2half(ld[cc][nrow]);
        }
    }
}

// ---------------- kernel 2: fused edge GEMM + adjacency aggregation --------
// R23: Round-0 proven structure (144us) with ONE register-budget-safe LDS
// diet: adjs LDS array removed; adj values loaded per-chunk directly into
// 4 f32x4 regs at chunk start (consumed by epilogue ~2000 cyc later —
// latency covered; L2-resident; same bytes -> FETCH unchanged).
// LDS ops 76 -> 71 per wave-chunk on the binding pipe (LDS ~92us of 144).
// Register law (R16-R22): arch must stay well under the 128 pin
// (120 baseline + ~10 here). No launch_bounds>2 (64-clamp spills), no
// global-bf (latency trap at 2 waves/SIMD), no held-prefetch windows
// (compiler discards or spills them).
__global__ __launch_bounds__(256, 2) void edge_gemm(
    const __half* __restrict__ U, const __half* __restrict__ V,
    const float* __restrict__ We2, const float* __restrict__ be2,
    const float* __restrict__ adj, float* __restrict__ aggws) {
    __shared__ __align__(16) char smem[57344];
    __half* Wt = (__half*)smem;                 // 32768 B: [64 n][256 k swz]
    __half* Us = (__half*)(smem + 32768);       //  8192 B: [16][256] swz
    __half* Vs = (__half*)(smem + 40960);       // 16384 B: [2][16][256] swz
    float* red = (float*)(smem + 40960);        // aliases Vs, post-loop only

    const int bid = blockIdx.x;
    const int hq_ = bid & 3;
    const int jt = (bid >> 2) & 31;
    const int b = bid >> 7;
    const int h_base = hq_ * 64;
    const int j_base = jt * 16;
    const int t = threadIdx.x;
    const int lane = t & 63;
    const int w = t >> 6;
    const int q = lane >> 4;
    const int l15 = lane & 15;

    const __half* Vb = V + (size_t)b * Nq * Hq;
    const float* adjb = adj + (size_t)b * Nq * Nq;

    const int srow = t >> 4;
    const int sc0 = (t & 15) * 2;

    {   // Wt staging (Round-0 verbatim)
        const int n = t & 63;
        const int swz = n & 31;
        for (int kk = (t >> 6); kk < 256; kk += 4) {
            float val = We2[kk * 256 + h_base + n];
            Wt[n * 256 + ((((kk >> 3) ^ swz)) << 3) + (kk & 7)] = __float2half(val);
        }
    }
    {   // Us staging (Round-0 verbatim)
        const uint4* gp = (const uint4*)(U + (size_t)(b * Nq + j_base + srow) * Hq);
        uint4 v0 = gp[sc0];
        uint4 v1 = gp[sc0 + 1];
        *(uint4*)&Us[srow * 256 + ((sc0 ^ srow) << 3)] = v0;
        *(uint4*)&Us[srow * 256 + (((sc0 + 1) ^ srow) << 3)] = v1;
    }

    float bias[4];
#pragma unroll
    for (int nt = 0; nt < 4; ++nt) bias[nt] = be2[h_base + nt * 16 + l15];

    f32x4 agg[4];
#pragma unroll
    for (int nt = 0; nt < 4; ++nt) agg[nt] = (f32x4){0.f, 0.f, 0.f, 0.f};

    uint4 pva, pvb;
    {   // stage chunk 0 (i rows 0..15)
        const uint4* gp = (const uint4*)(Vb + (size_t)srow * Hq);
        pva = gp[sc0]; pvb = gp[sc0 + 1];
        *(uint4*)&Vs[0 * 4096 + srow * 256 + ((sc0 ^ srow) << 3)] = pva;
        *(uint4*)&Vs[0 * 4096 + srow * 256 + (((sc0 + 1) ^ srow) << 3)] = pvb;
    }
    {   // preload chunk 1
        const uint4* gp = (const uint4*)(Vb + (size_t)(16 + srow) * Hq);
        pva = gp[sc0]; pvb = gp[sc0 + 1];
    }
    __syncthreads();

    const f32x4 zero4 = (f32x4){0.f, 0.f, 0.f, 0.f};

    for (int ch = 0; ch < 32; ++ch) {
        const int cur = ch & 1;
        const __half* Vcur = Vs + cur * 4096;

        // adj for this chunk: direct global->reg (L2-resident; consumed at
        // epilogue after the full ks loop -> latency covered)
        f32x4 av[4];
#pragma unroll
        for (int mi = 0; mi < 4; ++mi) {
            const int iv = w * 4 + mi;
            av[mi] = *(const f32x4*)&adjb[(size_t)(ch * 16 + iv) * Nq + j_base + q * 4];
        }

        f32x4 acc[4][4];
#pragma unroll
        for (int mi = 0; mi < 4; ++mi)
#pragma unroll
            for (int nt = 0; nt < 4; ++nt)
                acc[mi][nt] = (f32x4){bias[nt], bias[nt], bias[nt], bias[nt]};

#pragma unroll
        for (int ks = 0; ks < 8; ++ks) {
            const int c = ks * 4 + q;
            const f16x8 uvec = *(const f16x8*)&Us[l15 * 256 + ((c ^ l15) << 3)];
            f16x8 afrag[4];
#pragma unroll
            for (int mi = 0; mi < 4; ++mi) {
                const int iv = w * 4 + mi;
                const f16x8 vvec = *(const f16x8*)&Vcur[iv * 256 + ((c ^ iv) << 3)];
                afrag[mi] = hadd_relu(uvec, vvec);
            }
            f16x8 bf[4];
#pragma unroll
            for (int nt = 0; nt < 4; ++nt) {
                const int rn = nt * 16 + l15;
                bf[nt] = *(const f16x8*)&Wt[rn * 256 + ((c ^ (rn & 31)) << 3)];
            }
#pragma unroll
            for (int mi = 0; mi < 4; ++mi)
#pragma unroll
                for (int nt = 0; nt < 4; ++nt)
                    acc[mi][nt] = __builtin_amdgcn_mfma_f32_16x16x32_f16(
                        afrag[mi], bf[nt], acc[mi][nt], 0, 0, 0);
        }

        // epilogue: agg[j,h] += adj[i,j] * relu(z) — adj from registers
#pragma unroll
        for (int mi = 0; mi < 4; ++mi) {
#pragma unroll
            for (int nt = 0; nt < 4; ++nt) {
                const f32x4 rel = __builtin_elementwise_max(acc[mi][nt], zero4);
                agg[nt] = av[mi] * rel + agg[nt];
            }
        }

        if (ch < 31) {
            const int nxt = cur ^ 1;
            *(uint4*)&Vs[nxt * 4096 + srow * 256 + ((sc0 ^ srow) << 3)] = pva;
            *(uint4*)&Vs[nxt * 4096 + srow * 256 + (((sc0 + 1) ^ srow) << 3)] = pvb;
            if (ch < 30) {
                const int i_base = (ch + 2) * 16;
                const uint4* gp = (const uint4*)(Vb + (size_t)(i_base + srow) * Hq);
                pva = gp[sc0]; pvb = gp[sc0 + 1];
            }
        }
        __syncthreads();
    }

    // 4-way cross-wave reduction (red aliases Vs; loop-end barrier protects)
#pragma unroll
    for (int nt = 0; nt < 4; ++nt)
#pragma unroll
        for (int r = 0; r < 4; ++r)
            red[w * 1024 + (q * 4 + r) * 64 + nt * 16 + l15] = agg[nt][r];
    __syncthreads();
    {
        const int j = t >> 4;
        const int h0 = (t & 15) * 4;
        f32x4 s = *(const f32x4*)&red[0 * 1024 + j * 64 + h0];
        s += *(const f32x4*)&red[1 * 1024 + j * 64 + h0];
        s += *(const f32x4*)&red[2 * 1024 + j * 64 + h0];
        s += *(const f32x4*)&red[3 * 1024 + j * 64 + h0];
        *(f32x4*)&aggws[(size_t)(b * Nq + j_base + j) * Hq + h_base + h0] = s;
    }
}

// ---------------- kernel 3: MFMA node-MLP tail + log_softmax --------------
// Round-0 verbatim: 128 blocks x 16 nodes, per-wave h-slice 64.
__global__ __launch_bounds__(256) void tail_kernel(
    const float* __restrict__ aggws, const float* __restrict__ x,
    const __half* __restrict__ Wt16,
    const float* __restrict__ bn1, const float* __restrict__ bn2,
    const float* __restrict__ Wo1, const float* __restrict__ bo1,
    const float* __restrict__ Wo, const float* __restrict__ bo,
    float* __restrict__ out) {
    __shared__ __align__(16) __half actA[16 * 256];   // 8 KB
    __shared__ __align__(16) __half actB[16 * 256];   // 8 KB
    __shared__ float xs[16][4];
    __shared__ float part[4][16][4];
    __shared__ float s5[16][4];
    const int g0 = blockIdx.x * 16;
    const int t = threadIdx.x;
    const int lane = t & 63;
    const int w = t >> 6;
    const int q = lane >> 4;
    const int l15 = lane & 15;
    const int hb = w * 64;

    {
        const int row = t >> 4;
        const int g = (t & 15) * 2;
        const float* src = aggws + (size_t)(g0 + row) * 256;
        *(uint4*)&actA[row * 256 + ((g ^ row) << 3)] = cvt8h(src + g * 8);
        *(uint4*)&actA[row * 256 + (((g + 1) ^ row) << 3)] = cvt8h(src + g * 8 + 8);
    }
    if (t < 64) xs[t >> 2][t & 3] = x[(size_t)(g0 + (t >> 2)) * 4 + (t & 3)];
    __syncthreads();

    f32x4 acc[4];
    // layer n1
#pragma unroll
    for (int nt = 0; nt < 4; ++nt) {
        const float bv = bn1[hb + nt * 16 + l15];
        acc[nt] = (f32x4){bv, bv, bv, bv};
    }
#pragma unroll
    for (int ks = 0; ks < 8; ++ks) {
        const int c = ks * 4 + q;
        const f16x8 af = *(const f16x8*)&actA[l15 * 256 + ((c ^ l15) << 3)];
#pragma unroll
        for (int nt = 0; nt < 4; ++nt) {
            const f16x8 bf = *(const f16x8*)&Wt16[(size_t)(hb + nt * 16 + l15) * 256 + c * 8];
            acc[nt] = __builtin_amdgcn_mfma_f32_16x16x32_f16(af, bf, acc[nt], 0, 0, 0);
        }
    }
#pragma unroll
    for (int nt = 0; nt < 4; ++nt) {
        const int n = hb + nt * 16 + l15;
        const int g = n >> 3;
#pragma unroll
        for (int r = 0; r < 4; ++r) {
            const int row = q * 4 + r;
            actB[row * 256 + ((g ^ row) << 3) + (n & 7)] = __float2half(fmaxf(acc[nt][r], 0.f));
        }
    }
    __syncthreads();

    // layer n2
#pragma unroll
    for (int nt = 0; nt < 4; ++nt) {
        const float bv = bn2[hb + nt * 16 + l15];
        acc[nt] = (f32x4){bv, bv, bv, bv};
    }
#pragma unroll
    for (int ks = 0; ks < 8; ++ks) {
        const int c = ks * 4 + q;
        const f16x8 af = *(const f16x8*)&actB[l15 * 256 + ((c ^ l15) << 3)];
#pragma unroll
        for (int nt = 0; nt < 4; ++nt) {
            const f16x8 bf = *(const f16x8*)&Wt16[65536 + (size_t)(hb + nt * 16 + l15) * 256 + c * 8];
            acc[nt] = __builtin_amdgcn_mfma_f32_16x16x32_f16(af, bf, acc[nt], 0, 0, 0);
        }
    }
#pragma unroll
    for (int nt = 0; nt < 4; ++nt) {
        const int n = hb + nt * 16 + l15;
        const int g = n >> 3;
#pragma unroll
        for (int r = 0; r < 4; ++r) {
            const int row = q * 4 + r;
            actA[row * 256 + ((g ^ row) << 3) + (n & 7)] = __float2half(fmaxf(acc[nt][r], 0.f));
        }
    }
    __syncthreads();

    // layer o1 (x-part folded into init; no relu)
#pragma unroll
    for (int nt = 0; nt < 4; ++nt) {
        const int n = hb + nt * 16 + l15;
        const float bv = bo1[n];
        const float w0 = Wo1[0 * 256 + n], w1 = Wo1[1 * 256 + n];
        const float w2 = Wo1[2 * 256 + n], w3 = Wo1[3 * 256 + n];
#pragma unroll
        for (int r = 0; r < 4; ++r) {
            const int row = q * 4 + r;
            float v = bv;
            v = fmaf(xs[row][0], w0, v); v = fmaf(xs[row][1], w1, v);
            v = fmaf(xs[row][2], w2, v); v = fmaf(xs[row][3], w3, v);
            acc[nt][r] = v;
        }
    }
#pragma unroll
    for (int ks = 0; ks < 8; ++ks) {
        const int c = ks * 4 + q;
        const f16x8 af = *(const f16x8*)&actA[l15 * 256 + ((c ^ l15) << 3)];
#pragma unroll
        for (int nt = 0; nt < 4; ++nt) {
            const f16x8 bf = *(const f16x8*)&Wt16[2 * 65536 + (size_t)(hb + nt * 16 + l15) * 256 + c * 8];
            acc[nt] = __builtin_amdgcn_mfma_f32_16x16x32_f16(af, bf, acc[nt], 0, 0, 0);
        }
    }

    // layer o + log_softmax
    float p[4][4];
#pragma unroll
    for (int r = 0; r < 4; ++r)
#pragma unroll
        for (int d = 0; d < 4; ++d) p[r][d] = 0.f;
#pragma unroll
    for (int nt = 0; nt < 4; ++nt) {
        const int n = hb + nt * 16 + l15;
        const float4 wv = *(const float4*)&Wo[n * 4];
#pragma unroll
        for (int r = 0; r < 4; ++r) {
            p[r][0] = fmaf(acc[nt][r], wv.x, p[r][0]);
            p[r][1] = fmaf(acc[nt][r], wv.y, p[r][1]);
            p[r][2] = fmaf(acc[nt][r], wv.z, p[r][2]);
            p[r][3] = fmaf(acc[nt][r], wv.w, p[r][3]);
        }
    }
#pragma unroll
    for (int off = 1; off < 16; off <<= 1)
#pragma unroll
        for (int r = 0; r < 4; ++r)
#pragma unroll
            for (int d = 0; d < 4; ++d)
                p[r][d] += __shfl_xor(p[r][d], off);
    if (l15 == 0) {
#pragma unroll
        for (int r = 0; r < 4; ++r)
#pragma unroll
            for (int d = 0; d < 4; ++d) part[w][q * 4 + r][d] = p[r][d];
    }
    __syncthreads();
    if (t < 64) {
        const int row = t >> 2;
        const int d = t & 3;
        s5[row][d] = part[0][row][d] + part[1][row][d] + part[2][row][d]
                   + part[3][row][d] + bo[d];
    }
    __syncthreads();
    if (t < 16) {
        const float v0 = s5[t][0], v1 = s5[t][1], v2 = s5[t][2], v3 = s5[t][3];
        const float m = fmaxf(fmaxf(v0, v1), fmaxf(v2, v3));
        const float s = expf(v0 - m) + expf(v1 - m) + expf(v2 - m) + expf(v3 - m);
        const float lse = m + logf(s);
        float* op = out + (size_t)(g0 + t) * 4;
        op[0] = v0 - lse; op[1] = v1 - lse; op[2] = v2 - lse; op[3] = v3 - lse;
    }
}

extern "C" void kernel_launch(void* const* d_in, const int* in_sizes, int n_in,
                              void* d_out, int out_size, void* d_ws, size_t ws_size,
                              hipStream_t stream) {
    const float* x   = (const float*)d_in[0];
    const float* adj = (const float*)d_in[1];
    const float* We1 = (const float*)d_in[2];
    const float* be1 = (const float*)d_in[3];
    const float* We2 = (const float*)d_in[4];
    const float* be2 = (const float*)d_in[5];
    const float* Wn1 = (const float*)d_in[6];
    const float* bn1 = (const float*)d_in[7];
    const float* Wn2 = (const float*)d_in[8];
    const float* bn2 = (const float*)d_in[9];
    const float* Wo1 = (const float*)d_in[10];
    const float* bo1 = (const float*)d_in[11];
    const float* Wo  = (const float*)d_in[12];
    const float* bo  = (const float*)d_in[13];
    float* out = (float*)d_out;

    // ws: U fp16 1MB | V fp16 1MB | agg f32 2MB | Wt16 fp16 384KB
    __half* U = (__half*)d_ws;
    __half* V = U + (size_t)Bq * Nq * Hq;
    float* aggws = (float*)((char*)d_ws + (size_t)2 * Bq * Nq * Hq * sizeof(__half));
    __half* Wt16 = (__half*)((char*)d_ws + (size_t)4 * 1024 * 1024);

    prep_all<<<304, 256, 0, stream>>>(x, We1, be1, U, V, Wn1, Wn2, Wo1, Wt16);
    edge_gemm<<<512, 256, 0, stream>>>(U, V, We2, be2, adj, aggws);
    tail_kernel<<<128, 256, 0, stream>>>(aggws, x, Wt16, bn1, bn2, Wo1, bo1, Wo, bo, out);
}